// Round 6
// baseline (394.443 us; speedup 1.0000x reference)
//
#include <hip/hip_runtime.h>
#include <math.h>

#define T_SEQ 1024
#define FEAT  512
#define NH    8
#define DKH   64

typedef __attribute__((ext_vector_type(8))) short          bf16x8;
typedef _Float16 f16;
typedef __attribute__((ext_vector_type(8))) _Float16       f16x8;
typedef __attribute__((ext_vector_type(4))) float          f32x4;
typedef __attribute__((ext_vector_type(8))) unsigned short u16x8;
typedef __attribute__((ext_vector_type(4))) unsigned short u16x4;

__device__ __forceinline__ float bf2f(unsigned short u) {
    union { unsigned int i; float f; } x; x.i = ((unsigned int)u) << 16; return x.f;
}
__device__ __forceinline__ unsigned short f2bf(float f) {
    union { float f; unsigned int i; } x; x.f = f;
    unsigned int r = x.i + 0x7FFFu + ((x.i >> 16) & 1u);
    return (unsigned short)(r >> 16);
}
__device__ __forceinline__ unsigned short f2h_bits(float f) {
    const f16 h = (f16)f;
    union { f16 h; unsigned short u; } x; x.h = h; return x.u;
}

typedef const __attribute__((address_space(1))) unsigned int* gas_ptr;
typedef __attribute__((address_space(3))) unsigned int*       las_ptr;
__device__ __forceinline__ void glds16(const unsigned short* g, unsigned short* l) {
    __builtin_amdgcn_global_load_lds((gas_ptr)(const void*)g, (las_ptr)(void*)l, 16, 0, 0);
}

// ---------------------------------------------------------------------------
// fp32 -> (hi, lo) bf16 split: 5 weights (grid.y 0..4) then 4 inputs (5..8)
// ---------------------------------------------------------------------------
struct SplitPack {
    const float*    src[9];
    unsigned short* hi[9];
    unsigned short* lo[9];
    int             n4[9];
};

__global__ __launch_bounds__(256)
void split_f32(SplitPack pk) {
    const int ten = blockIdx.y;
    const int n4  = pk.n4[ten];
    const float4* s = (const float4*)pk.src[ten];
    u16x4* dh = (u16x4*)pk.hi[ten];
    u16x4* dl = (u16x4*)pk.lo[ten];
    for (int i = blockIdx.x * blockDim.x + threadIdx.x; i < n4;
         i += gridDim.x * blockDim.x) {
        const float4 v = s[i];
        float a[4] = {v.x, v.y, v.z, v.w};
        u16x4 h, l;
#pragma unroll
        for (int j = 0; j < 4; ++j) {
            h[j] = f2bf(a[j]);
            l[j] = f2bf(a[j] - bf2f(h[j]));
        }
        dh[i] = h; dl[i] = l;
    }
}

// ---------------------------------------------------------------------------
// Pre-split bf16 GEMM: C[M,N] = (Ah+Al)[M,K] @ (Wh+Wl)[N,K]^T (+bias)
// 3-term split product (AhBh + AhBl + AlBh), fp32 accum.
// Tile 128Mx64N, BK=32, 256 thr / 4 waves (each 64x32 = 4x2 frags).
// Staging: global_load_lds dwordx4, linear LDS (64B row stride -> bank-even),
// 2-phase double buffer (STAGE next || compute current, 1 barrier/step).
// OUTMODE 0: fp32 C; 1: f16 C; 2: f16 V^T layout [b][col][t]
// ---------------------------------------------------------------------------
#define GBUF 12288   // u16 per buffer: Ah 4096 | Al 4096 | Bh 2048 | Bl 2048

template<int OUTMODE>
__global__ __launch_bounds__(256)
void gemm_ps(const unsigned short* __restrict__ Agh,
             const unsigned short* __restrict__ Agl,
             const unsigned short* __restrict__ Wh,
             const unsigned short* __restrict__ Wl,
             const float* __restrict__ bias,
             void* __restrict__ Cout, int M, int N, int K)
{
    __shared__ unsigned short lds[2 * GBUF];

    const int tid  = threadIdx.x;
    const int w    = tid >> 6, lane = tid & 63, g = lane >> 4, c = lane & 15;
    const int m0   = blockIdx.x * 128, n0 = blockIdx.y * 64;
    const int wr   = (w >> 1) * 64, wc = (w & 1) * 32;

    f32x4 acc[4][2];
#pragma unroll
    for (int m = 0; m < 4; ++m)
#pragma unroll
        for (int n = 0; n < 2; ++n)
#pragma unroll
            for (int r = 0; r < 4; ++r) acc[m][n][r] = 0.f;

    auto STAGE = [&](unsigned short* base, int kc) {
        const int k0 = kc * 32;
#pragma unroll
        for (int q = 0; q < 2; ++q) {
            const int chunk = q * 256 + w * 64 + lane;       // 0..511
            const int row = chunk >> 2, p = chunk & 3;
            const int gra = m0 + row;
            const int gr  = (gra < M) ? gra : (M - 1);
            const size_t go = (size_t)gr * K + k0 + p * 8;
            glds16(Agh + go, base + chunk * 8);
            glds16(Agl + go, base + 4096 + chunk * 8);
        }
        {
            const int chunk = w * 64 + lane;                 // 0..255
            const int row = chunk >> 2, p = chunk & 3;
            const size_t go = (size_t)(n0 + row) * K + k0 + p * 8;
            glds16(Wh + go, base + 8192 + chunk * 8);
            glds16(Wl + go, base + 10240 + chunk * 8);
        }
    };

    STAGE(lds, 0);
    __syncthreads();           // drains vmcnt(0): buf0 ready

    const int nk = K / 32;
    int cur = 0;
    for (int kc = 0; kc < nk; ++kc) {
        if (kc + 1 < nk) STAGE(lds + (cur ^ 1) * GBUF, kc + 1);

        const unsigned short* Bs = lds + cur * GBUF;
        bf16x8 ah[4], al[4], bh[2], bl[2];
#pragma unroll
        for (int m = 0; m < 4; ++m) {
            const int ro = (wr + 16 * m + c) * 32 + g * 8;
            ah[m] = *(const bf16x8*)&Bs[ro];
            al[m] = *(const bf16x8*)&Bs[4096 + ro];
        }
#pragma unroll
        for (int n = 0; n < 2; ++n) {
            const int ro = (wc + 16 * n + c) * 32 + g * 8;
            bh[n] = *(const bf16x8*)&Bs[8192 + ro];
            bl[n] = *(const bf16x8*)&Bs[10240 + ro];
        }
#pragma unroll
        for (int m = 0; m < 4; ++m)
#pragma unroll
            for (int n = 0; n < 2; ++n) {
                acc[m][n] = __builtin_amdgcn_mfma_f32_16x16x32_bf16(ah[m], bh[n], acc[m][n], 0, 0, 0);
                acc[m][n] = __builtin_amdgcn_mfma_f32_16x16x32_bf16(ah[m], bl[n], acc[m][n], 0, 0, 0);
                acc[m][n] = __builtin_amdgcn_mfma_f32_16x16x32_bf16(al[m], bh[n], acc[m][n], 0, 0, 0);
            }

        __syncthreads();       // all reads of cur done AND next buf (vmcnt) ready
        cur ^= 1;
    }

#pragma unroll
    for (int n = 0; n < 2; ++n) {
        const int gcol = n0 + wc + 16 * n + c;
        const float bb = bias ? bias[gcol] : 0.f;
#pragma unroll
        for (int m = 0; m < 4; ++m) {
            if (OUTMODE == 2) {
                const int grb = m0 + wr + 16 * m + 4 * g;
                const int bidx = grb >> 10, t = grb & 1023;
                u16x4 pk4;
#pragma unroll
                for (int r = 0; r < 4; ++r) pk4[r] = f2h_bits(acc[m][n][r] + bb);
                *(u16x4*)&((unsigned short*)Cout)[((size_t)(bidx * FEAT + gcol)) * T_SEQ + t] = pk4;
            } else {
#pragma unroll
                for (int r = 0; r < 4; ++r) {
                    const int gr = m0 + wr + 16 * m + 4 * g + r;
                    if (gr < M) {
                        const float v = acc[m][n][r] + bb;
                        if (OUTMODE == 0) ((float*)Cout)[(size_t)gr * N + gcol] = v;
                        else ((unsigned short*)Cout)[(size_t)gr * N + gcol] = f2h_bits(v);
                    }
                }
            }
        }
    }
}

// ---------------------------------------------------------------------------
// fp16-MFMA relative-position flash attention — R5-verified structure
// (178us: strides 72, row-major bdb @132, separate ps, Q-register hoist).
// ONLY change this round: epilogue emits split (xh, xl) bf16 for the
// pre-split out-GEMM (same store bytes as the old fp32 x).
// ---------------------------------------------------------------------------
#define AST  72
#define BDST 132

__global__ __launch_bounds__(256)
void attn_f16(const unsigned short* __restrict__ qb,
              const unsigned short* __restrict__ kb,
              const unsigned short* __restrict__ vtg,   // V^T [b][feat][t], f16
              const unsigned short* __restrict__ pb,    // [2047][FEAT], f16
              const int* __restrict__ mask,
              const float* __restrict__ pbu, const float* __restrict__ pbv,
              unsigned short* __restrict__ xh, unsigned short* __restrict__ xl)
{
    extern __shared__ unsigned short sm[];
    unsigned short* kt  = sm;                 // 64*AST
    unsigned short* vtT = kt  + 64 * AST;     // 64*AST
    unsigned short* pt  = vtT + 64 * AST;     // 128*AST
    unsigned short* ps  = pt  + 128 * AST;    // 64*AST
    unsigned short* bdb = ps  + 64 * AST;     // 64*BDST
    f16* bdf = (f16*)bdb;
    f16* psf = (f16*)ps;

    const int tid = threadIdx.x;
    const int w = tid >> 6, lane = tid & 63, g = lane >> 4, c = lane & 15;
    const int t0 = blockIdx.x * 64;
    const int b  = blockIdx.y >> 3, h = blockIdx.y & 7;

    const unsigned short* ksrc = kb + ((size_t)b * T_SEQ) * FEAT + h * DKH;
    const unsigned short* vsrc = vtg + ((size_t)(b * FEAT + h * DKH)) * T_SEQ;
    const unsigned short* psrc = pb + h * DKH;

    // ---- Q fragments directly to registers (loop-invariant; A-frag row = c)
    f16x8 aq0, aq1, av0, av1;
    {
        const unsigned short* qp =
            qb + ((size_t)(b * T_SEQ + t0 + 16 * w + c)) * FEAT + h * DKH + 8 * g;
        const f16x8 q0 = *(const f16x8*)qp;
        const f16x8 q1 = *(const f16x8*)(qp + 32);
        const float* pu = pbu + h * DKH + 8 * g;
        const float* pv = pbv + h * DKH + 8 * g;
#pragma unroll
        for (int j = 0; j < 8; ++j) {
            const float f0 = (float)q0[j], f1 = (float)q1[j];
            aq0[j] = (f16)(f0 + pu[j]);       av0[j] = (f16)(f0 + pv[j]);
            aq1[j] = (f16)(f1 + pu[j + 32]);  av1[j] = (f16)(f1 + pv[j + 32]);
        }
    }

    f32x4 accO[4];
    float m_r[4], l_r[4];
#pragma unroll
    for (int n = 0; n < 4; ++n)
#pragma unroll
        for (int r = 0; r < 4; ++r) accO[n][r] = 0.f;
#pragma unroll
    for (int r = 0; r < 4; ++r) { m_r[r] = -3.0e38f; l_r[r] = 0.f; }

    for (int st = 0; st < 16; ++st) {
        const int s0 = st * 64;
        const int pbase = (T_SEQ - DKH) - t0 + s0;   // p row = pbase + (63 - ti + si)
        __syncthreads();   // A: prev-iter PV reads done
#pragma unroll
        for (int q2 = 0; q2 < 2; ++q2) {
            const int id = tid + 256 * q2, row = id >> 3, chq = id & 7;
            *(u16x8*)&kt[row * AST + chq * 8] =
                *(const u16x8*)&ksrc[(size_t)(s0 + row) * FEAT + chq * 8];
            *(u16x8*)&vtT[row * AST + chq * 8] =
                *(const u16x8*)&vsrc[(size_t)row * T_SEQ + s0 + chq * 8];
        }
#pragma unroll
        for (int q2 = 0; q2 < 4; ++q2) {
            const int id = tid + 256 * q2, prow = id >> 3, chq = id & 7;
            u16x8 p8;
            if (prow < 127)
                p8 = *(const u16x8*)&psrc[(size_t)(pbase + prow) * FEAT + chq * 8];
            else {
#pragma unroll
                for (int j = 0; j < 8; ++j) p8[j] = 0;
            }
            *(u16x8*)&pt[prow * AST + chq * 8] = p8;
        }
        __syncthreads();   // B: tiles ready

        // ---- AC = (q+u) K^T
        f32x4 acS[4];
#pragma unroll
        for (int j = 0; j < 4; ++j)
#pragma unroll
            for (int r = 0; r < 4; ++r) acS[j][r] = 0.f;
#pragma unroll
        for (int j = 0; j < 4; ++j) {
            const f16x8 b0 = *(const f16x8*)&kt[(16 * j + c) * AST + 8 * g];
            const f16x8 b1 = *(const f16x8*)&kt[(16 * j + c) * AST + 32 + 8 * g];
            acS[j] = __builtin_amdgcn_mfma_f32_16x16x32_f16(aq0, b0, acS[j], 0, 0, 0);
            acS[j] = __builtin_amdgcn_mfma_f32_16x16x32_f16(aq1, b1, acS[j], 0, 0, 0);
        }

        // ---- BD = (q+v) P_window^T -> bdb row-major [t][p]
#pragma unroll
        for (int jj = 0; jj < 8; ++jj) {
            f32x4 bda;
#pragma unroll
            for (int r = 0; r < 4; ++r) bda[r] = 0.f;
            const f16x8 b0 = *(const f16x8*)&pt[(16 * jj + c) * AST + 8 * g];
            const f16x8 b1 = *(const f16x8*)&pt[(16 * jj + c) * AST + 32 + 8 * g];
            bda = __builtin_amdgcn_mfma_f32_16x16x32_f16(av0, b0, bda, 0, 0, 0);
            bda = __builtin_amdgcn_mfma_f32_16x16x32_f16(av1, b1, bda, 0, 0, 0);
#pragma unroll
            for (int r = 0; r < 4; ++r)
                bdf[(16 * w + 4 * g + r) * BDST + 16 * jj + c] = (f16)bda[r];
        }
        __syncthreads();   // C: bdb visible

        // ---- online softmax; rows ti = 16w+4g+r, cols si = 16j+c
        int mk[4];
#pragma unroll
        for (int j = 0; j < 4; ++j) mk[j] = mask[b * T_SEQ + s0 + 16 * j + c];
#pragma unroll
        for (int r = 0; r < 4; ++r) {
            const int ti = 16 * w + 4 * g + r;
            float sv[4];
#pragma unroll
            for (int j = 0; j < 4; ++j) {
                const float bdv = (float)bdf[ti * BDST + (63 - ti + 16 * j + c)];
                sv[j] = (mk[j] == 0) ? -1.0e30f : (acS[j][r] + bdv) * 0.125f;
            }
            float mx = fmaxf(fmaxf(sv[0], sv[1]), fmaxf(sv[2], sv[3]));
            mx = fmaxf(mx, __shfl_xor(mx, 1)); mx = fmaxf(mx, __shfl_xor(mx, 2));
            mx = fmaxf(mx, __shfl_xor(mx, 4)); mx = fmaxf(mx, __shfl_xor(mx, 8));
            const float mnew = fmaxf(m_r[r], mx);
            const float corr = __expf(m_r[r] - mnew);
            m_r[r] = mnew;
            float rs = 0.f;
#pragma unroll
            for (int j = 0; j < 4; ++j) {
                const float e = (mk[j] == 0) ? 0.f : __expf(sv[j] - mnew);
                rs += e;
                psf[ti * AST + 16 * j + c] = (f16)e;
            }
            rs += __shfl_xor(rs, 1); rs += __shfl_xor(rs, 2);
            rs += __shfl_xor(rs, 4); rs += __shfl_xor(rs, 8);
            l_r[r] = l_r[r] * corr + rs;
#pragma unroll
            for (int n = 0; n < 4; ++n) accO[n][r] *= corr;
        }
        __syncthreads();   // D: P visible

        // ---- PV: O += P V
        const f16x8 pa0 = *(const f16x8*)&ps[(16 * w + c) * AST + 8 * g];
        const f16x8 pa1 = *(const f16x8*)&ps[(16 * w + c) * AST + 32 + 8 * g];
#pragma unroll
        for (int n = 0; n < 4; ++n) {
            const f16x8 b0 = *(const f16x8*)&vtT[(16 * n + c) * AST + 8 * g];
            const f16x8 b1 = *(const f16x8*)&vtT[(16 * n + c) * AST + 32 + 8 * g];
            accO[n] = __builtin_amdgcn_mfma_f32_16x16x32_f16(pa0, b0, accO[n], 0, 0, 0);
            accO[n] = __builtin_amdgcn_mfma_f32_16x16x32_f16(pa1, b1, accO[n], 0, 0, 0);
        }
    }

    // ---- epilogue: x split into (hi, lo) bf16 for the out-GEMM
#pragma unroll
    for (int r = 0; r < 4; ++r) {
        const float inv = (l_r[r] > 0.f) ? 1.0f / l_r[r] : 0.f;
        const int t = t0 + 16 * w + 4 * g + r;
#pragma unroll
        for (int n = 0; n < 4; ++n) {
            const float xv = accO[n][r] * inv;
            const size_t idx = ((size_t)(b * T_SEQ + t)) * FEAT + h * DKH + 16 * n + c;
            const unsigned short hp = f2bf(xv);
            xh[idx] = hp;
            xl[idx] = f2bf(xv - bf2f(hp));
        }
    }
}

// ---------------------------------------------------------------------------
extern "C" void kernel_launch(void* const* d_in, const int* in_sizes, int n_in,
                              void* d_out, int out_size, void* d_ws, size_t ws_size,
                              hipStream_t stream)
{
    (void)in_sizes; (void)n_in; (void)out_size; (void)ws_size;
    const float* query   = (const float*)d_in[0];
    const float* key_in  = (const float*)d_in[1];
    const float* value   = (const float*)d_in[2];
    const float* pos_emb = (const float*)d_in[3];
    const int*   mask    = (const int*)  d_in[4];
    const float* Wq = (const float*)d_in[5];
    const float* bq = (const float*)d_in[6];
    const float* Wk = (const float*)d_in[7];
    const float* bk = (const float*)d_in[8];
    const float* Wv = (const float*)d_in[9];
    const float* bv = (const float*)d_in[10];
    const float* Wo = (const float*)d_in[11];
    const float* bo = (const float*)d_in[12];
    const float* Wp = (const float*)d_in[13];
    const float* pbu = (const float*)d_in[14];
    const float* pbv = (const float*)d_in[15];
    float* out = (float*)d_out;

    const size_t NTOK = (size_t)8 * T_SEQ;       // 8192
    char* wsp = (char*)d_ws;
    size_t off = 0;
    auto alloc = [&](size_t bytes) { char* p = wsp + off; off += (bytes + 255) & ~255ull; return p; };

    unsigned short* qbf = (unsigned short*)alloc(NTOK * FEAT * 2);         // f16
    unsigned short* kbf = (unsigned short*)alloc(NTOK * FEAT * 2);         // f16
    unsigned short* vTb = (unsigned short*)alloc(NTOK * FEAT * 2);         // f16 [b][feat][t]
    unsigned short* pbf = (unsigned short*)alloc((size_t)2047 * FEAT * 2); // f16
    unsigned short* wh[5]; unsigned short* wl[5];
    for (int i = 0; i < 5; ++i) {
        wh[i] = (unsigned short*)alloc((size_t)FEAT * FEAT * 2);
        wl[i] = (unsigned short*)alloc((size_t)FEAT * FEAT * 2);
    }
    unsigned short* iqh = (unsigned short*)alloc(NTOK * FEAT * 2);
    unsigned short* iql = (unsigned short*)alloc(NTOK * FEAT * 2);
    unsigned short* ikh = (unsigned short*)alloc(NTOK * FEAT * 2);
    unsigned short* ikl = (unsigned short*)alloc(NTOK * FEAT * 2);
    unsigned short* ivh = (unsigned short*)alloc(NTOK * FEAT * 2);
    unsigned short* ivl = (unsigned short*)alloc(NTOK * FEAT * 2);
    unsigned short* iph = (unsigned short*)alloc((size_t)2047 * FEAT * 2);
    unsigned short* ipl = (unsigned short*)alloc((size_t)2047 * FEAT * 2);
    // x split reuses the query split (dead after the q-projection GEMM)
    unsigned short* xh = iqh;
    unsigned short* xl = iql;

    SplitPack sp;
    const float* wsrc[9] = {Wq, Wk, Wv, Wp, Wo, query, key_in, value, pos_emb};
    unsigned short* hdst[9] = {wh[0], wh[1], wh[2], wh[3], wh[4], iqh, ikh, ivh, iph};
    unsigned short* ldst[9] = {wl[0], wl[1], wl[2], wl[3], wl[4], iql, ikl, ivl, ipl};
    for (int i = 0; i < 9; ++i) {
        sp.src[i] = wsrc[i]; sp.hi[i] = hdst[i]; sp.lo[i] = ldst[i];
        sp.n4[i] = (i < 5) ? (FEAT * FEAT / 4)
                           : ((i < 8) ? (int)(NTOK * FEAT / 4) : (2047 * FEAT / 4));
    }
    split_f32<<<dim3(256, 9), 256, 0, stream>>>(sp);

    gemm_ps<1><<<dim3(64, 8), 256, 0, stream>>>(iqh, iql, wh[0], wl[0], bq, qbf, 8192, FEAT, FEAT);
    gemm_ps<1><<<dim3(64, 8), 256, 0, stream>>>(ikh, ikl, wh[1], wl[1], bk, kbf, 8192, FEAT, FEAT);
    gemm_ps<2><<<dim3(64, 8), 256, 0, stream>>>(ivh, ivl, wh[2], wl[2], bv, vTb, 8192, FEAT, FEAT);
    gemm_ps<1><<<dim3(16, 8), 256, 0, stream>>>(iph, ipl, wh[3], wl[3], nullptr, pbf, 2047, FEAT, FEAT);

    const int lds_bytes = (64 * AST * 3 + 128 * AST + 64 * BDST) * 2;   // 62976
    hipFuncSetAttribute((const void*)attn_f16,
                        hipFuncAttributeMaxDynamicSharedMemorySize, lds_bytes);
    attn_f16<<<dim3(16, 64), 256, lds_bytes, stream>>>(qbf, kbf, vTb, pbf,
                                                       mask, pbu, pbv, xh, xl);

    gemm_ps<0><<<dim3(64, 8), 256, 0, stream>>>(xh, xl, wh[4], wl[4], bo, out, 8192, FEAT, FEAT);
}

// Round 9
// 340.878 us; speedup vs baseline: 1.1571x; 1.1571x over previous
//
#include <hip/hip_runtime.h>
#include <math.h>

#define T_SEQ 1024
#define FEAT  512
#define NH    8
#define DKH   64

typedef __attribute__((ext_vector_type(8))) short          bf16x8;
typedef _Float16 f16;
typedef __attribute__((ext_vector_type(8))) _Float16       f16x8;
typedef __attribute__((ext_vector_type(4))) float          f32x4;
typedef __attribute__((ext_vector_type(8))) unsigned short u16x8;
typedef __attribute__((ext_vector_type(4))) unsigned short u16x4;

__device__ __forceinline__ float bf2f(unsigned short u) {
    union { unsigned int i; float f; } x; x.i = ((unsigned int)u) << 16; return x.f;
}
__device__ __forceinline__ unsigned short f2bf(float f) {
    union { float f; unsigned int i; } x; x.f = f;
    unsigned int r = x.i + 0x7FFFu + ((x.i >> 16) & 1u);
    return (unsigned short)(r >> 16);
}
__device__ __forceinline__ unsigned short f2h_bits(float f) {
    const f16 h = (f16)f;
    union { f16 h; unsigned short u; } x; x.h = h; return x.u;
}

typedef const __attribute__((address_space(1))) unsigned int* gas_ptr;
typedef __attribute__((address_space(3))) unsigned int*       las_ptr;
__device__ __forceinline__ void glds16(const unsigned short* g, unsigned short* l) {
    __builtin_amdgcn_global_load_lds((gas_ptr)(const void*)g, (las_ptr)(void*)l, 16, 0, 0);
}

// ---------------------------------------------------------------------------
// fp32 -> (hi, lo) bf16 split: 5 weights (grid.y 0..4) then 4 inputs (5..8)
// ---------------------------------------------------------------------------
struct SplitPack {
    const float*    src[9];
    unsigned short* hi[9];
    unsigned short* lo[9];
    int             n4[9];
};

__global__ __launch_bounds__(256)
void split_f32(SplitPack pk) {
    const int ten = blockIdx.y;
    const int n4  = pk.n4[ten];
    const float4* s = (const float4*)pk.src[ten];
    u16x4* dh = (u16x4*)pk.hi[ten];
    u16x4* dl = (u16x4*)pk.lo[ten];
    for (int i = blockIdx.x * blockDim.x + threadIdx.x; i < n4;
         i += gridDim.x * blockDim.x) {
        const float4 v = s[i];
        float a[4] = {v.x, v.y, v.z, v.w};
        u16x4 h, l;
#pragma unroll
        for (int j = 0; j < 4; ++j) {
            h[j] = f2bf(a[j]);
            l[j] = f2bf(a[j] - bf2f(h[j]));
        }
        dh[i] = h; dl[i] = l;
    }
}

// ---------------------------------------------------------------------------
// Pre-split bf16 GEMM: C[M,N] = (Ah+Al)[M,K] @ (Wh+Wl)[N,K]^T (+bias)
// 3-term split product (AhBh + AhBl + AlBh), fp32 accum.
// Tile 128Mx64N, BK=32, 256 thr / 4 waves (each 64x32 = 4x2 frags).
// Staging: global_load_lds dwordx4, linear LDS, 2-phase double buffer.
// OUTMODE 0: fp32 C; 1: f16 C; 2: f16 V^T layout [b][col][t]
// ---------------------------------------------------------------------------
#define GBUF 12288   // u16 per buffer: Ah 4096 | Al 4096 | Bh 2048 | Bl 2048

template<int OUTMODE>
__global__ __launch_bounds__(256)
void gemm_ps(const unsigned short* __restrict__ Agh,
             const unsigned short* __restrict__ Agl,
             const unsigned short* __restrict__ Wh,
             const unsigned short* __restrict__ Wl,
             const float* __restrict__ bias,
             void* __restrict__ Cout, int M, int N, int K)
{
    __shared__ unsigned short lds[2 * GBUF];

    const int tid  = threadIdx.x;
    const int w    = tid >> 6, lane = tid & 63, g = lane >> 4, c = lane & 15;
    const int m0   = blockIdx.x * 128, n0 = blockIdx.y * 64;
    const int wr   = (w >> 1) * 64, wc = (w & 1) * 32;

    f32x4 acc[4][2];
#pragma unroll
    for (int m = 0; m < 4; ++m)
#pragma unroll
        for (int n = 0; n < 2; ++n)
#pragma unroll
            for (int r = 0; r < 4; ++r) acc[m][n][r] = 0.f;

    auto STAGE = [&](unsigned short* base, int kc) {
        const int k0 = kc * 32;
#pragma unroll
        for (int q = 0; q < 2; ++q) {
            const int chunk = q * 256 + w * 64 + lane;       // 0..511
            const int row = chunk >> 2, p = chunk & 3;
            const int gra = m0 + row;
            const int gr  = (gra < M) ? gra : (M - 1);
            const size_t go = (size_t)gr * K + k0 + p * 8;
            glds16(Agh + go, base + chunk * 8);
            glds16(Agl + go, base + 4096 + chunk * 8);
        }
        {
            const int chunk = w * 64 + lane;                 // 0..255
            const int row = chunk >> 2, p = chunk & 3;
            const size_t go = (size_t)(n0 + row) * K + k0 + p * 8;
            glds16(Wh + go, base + 8192 + chunk * 8);
            glds16(Wl + go, base + 10240 + chunk * 8);
        }
    };

    STAGE(lds, 0);
    __syncthreads();           // drains vmcnt(0): buf0 ready

    const int nk = K / 32;
    int cur = 0;
    for (int kc = 0; kc < nk; ++kc) {
        if (kc + 1 < nk) STAGE(lds + (cur ^ 1) * GBUF, kc + 1);

        const unsigned short* Bs = lds + cur * GBUF;
        bf16x8 ah[4], al[4], bh[2], bl[2];
#pragma unroll
        for (int m = 0; m < 4; ++m) {
            const int ro = (wr + 16 * m + c) * 32 + g * 8;
            ah[m] = *(const bf16x8*)&Bs[ro];
            al[m] = *(const bf16x8*)&Bs[4096 + ro];
        }
#pragma unroll
        for (int n = 0; n < 2; ++n) {
            const int ro = (wc + 16 * n + c) * 32 + g * 8;
            bh[n] = *(const bf16x8*)&Bs[8192 + ro];
            bl[n] = *(const bf16x8*)&Bs[10240 + ro];
        }
#pragma unroll
        for (int m = 0; m < 4; ++m)
#pragma unroll
            for (int n = 0; n < 2; ++n) {
                acc[m][n] = __builtin_amdgcn_mfma_f32_16x16x32_bf16(ah[m], bh[n], acc[m][n], 0, 0, 0);
                acc[m][n] = __builtin_amdgcn_mfma_f32_16x16x32_bf16(ah[m], bl[n], acc[m][n], 0, 0, 0);
                acc[m][n] = __builtin_amdgcn_mfma_f32_16x16x32_bf16(al[m], bh[n], acc[m][n], 0, 0, 0);
            }

        __syncthreads();       // all reads of cur done AND next buf (vmcnt) ready
        cur ^= 1;
    }

#pragma unroll
    for (int n = 0; n < 2; ++n) {
        const int gcol = n0 + wc + 16 * n + c;
        const float bb = bias ? bias[gcol] : 0.f;
#pragma unroll
        for (int m = 0; m < 4; ++m) {
            if (OUTMODE == 2) {
                const int grb = m0 + wr + 16 * m + 4 * g;
                const int bidx = grb >> 10, t = grb & 1023;
                u16x4 pk4;
#pragma unroll
                for (int r = 0; r < 4; ++r) pk4[r] = f2h_bits(acc[m][n][r] + bb);
                *(u16x4*)&((unsigned short*)Cout)[((size_t)(bidx * FEAT + gcol)) * T_SEQ + t] = pk4;
            } else {
#pragma unroll
                for (int r = 0; r < 4; ++r) {
                    const int gr = m0 + wr + 16 * m + 4 * g + r;
                    if (gr < M) {
                        const float v = acc[m][n][r] + bb;
                        if (OUTMODE == 0) ((float*)Cout)[(size_t)gr * N + gcol] = v;
                        else ((unsigned short*)Cout)[(size_t)gr * N + gcol] = f2h_bits(v);
                    }
                }
            }
        }
    }
}

// ---------------------------------------------------------------------------
// fp16-MFMA relative-position flash attention, in-register rel-shift.
// Index algebra: lane (g,c) BD output bdacc[q][r] = BD[ti][pw=16(q+3-w)+c],
// ti = 16w+4g+r, si = pw-63+ti = 16q + c - delta, delta = 15-4g-r.
// => lane owns score columns si == (c-delta) mod 16; only 5 window blocks
// jj in [3-w, 7-w] are ever needed (was 8). AC value fetched by one __shfl
// per (j,r) from lane (g, (c-delta)&15); mask folded in pre-shuffle.
// bd stays fp32 in registers (no bdb LDS, no barrier C).
// LDS (u16, strides mult of 8 -> 16B-aligned b128): kt 64x72, vtT 64x72,
// pt 128x72, ps 64x72 = 46080 B -> 3 blocks/CU.
// ---------------------------------------------------------------------------
#define AST  72

__global__ __launch_bounds__(256)
void attn_f16(const unsigned short* __restrict__ qb,
              const unsigned short* __restrict__ kb,
              const unsigned short* __restrict__ vtg,   // V^T [b][feat][t], f16
              const unsigned short* __restrict__ pb,    // [2047][FEAT], f16
              const int* __restrict__ mask,
              const float* __restrict__ pbu, const float* __restrict__ pbv,
              unsigned short* __restrict__ xh, unsigned short* __restrict__ xl)
{
    extern __shared__ unsigned short sm[];
    unsigned short* kt  = sm;                 // 64*AST
    unsigned short* vtT = kt  + 64 * AST;     // 64*AST
    unsigned short* pt  = vtT + 64 * AST;     // 128*AST
    unsigned short* ps  = pt  + 128 * AST;    // 64*AST
    f16* psf = (f16*)ps;

    const int tid = threadIdx.x;
    const int w = tid >> 6, lane = tid & 63, g = lane >> 4, c = lane & 15;
    const int t0 = blockIdx.x * 64;
    const int b  = blockIdx.y >> 3, h = blockIdx.y & 7;

    const unsigned short* ksrc = kb + ((size_t)b * T_SEQ) * FEAT + h * DKH;
    const unsigned short* vsrc = vtg + ((size_t)(b * FEAT + h * DKH)) * T_SEQ;
    const unsigned short* psrc = pb + h * DKH;

    // ---- Q fragments directly to registers (loop-invariant; A-frag row = c)
    f16x8 aq0, aq1, av0, av1;
    {
        const unsigned short* qp =
            qb + ((size_t)(b * T_SEQ + t0 + 16 * w + c)) * FEAT + h * DKH + 8 * g;
        const f16x8 q0 = *(const f16x8*)qp;
        const f16x8 q1 = *(const f16x8*)(qp + 32);
        const float* pu = pbu + h * DKH + 8 * g;
        const float* pv = pbv + h * DKH + 8 * g;
#pragma unroll
        for (int j = 0; j < 8; ++j) {
            const float f0 = (float)q0[j], f1 = (float)q1[j];
            aq0[j] = (f16)(f0 + pu[j]);       av0[j] = (f16)(f0 + pv[j]);
            aq1[j] = (f16)(f1 + pu[j + 32]);  av1[j] = (f16)(f1 + pv[j + 32]);
        }
    }

    f32x4 accO[4];
    float m_r[4], l_r[4];
#pragma unroll
    for (int n = 0; n < 4; ++n)
#pragma unroll
        for (int r = 0; r < 4; ++r) accO[n][r] = 0.f;
#pragma unroll
    for (int r = 0; r < 4; ++r) { m_r[r] = -3.0e38f; l_r[r] = 0.f; }

    for (int st = 0; st < 16; ++st) {
        const int s0 = st * 64;
        const int pbase = (T_SEQ - DKH) - t0 + s0;   // p row = pbase + (63 - ti + si)
        __syncthreads();   // A: prev-iter PV/BD reads done
#pragma unroll
        for (int q2 = 0; q2 < 2; ++q2) {
            const int id = tid + 256 * q2, row = id >> 3, chq = id & 7;
            *(u16x8*)&kt[row * AST + chq * 8] =
                *(const u16x8*)&ksrc[(size_t)(s0 + row) * FEAT + chq * 8];
            *(u16x8*)&vtT[row * AST + chq * 8] =
                *(const u16x8*)&vsrc[(size_t)row * T_SEQ + s0 + chq * 8];
        }
#pragma unroll
        for (int q2 = 0; q2 < 4; ++q2) {
            const int id = tid + 256 * q2, prow = id >> 3, chq = id & 7;
            u16x8 p8;
            if (prow < 127)
                p8 = *(const u16x8*)&psrc[(size_t)(pbase + prow) * FEAT + chq * 8];
            else {
#pragma unroll
                for (int j = 0; j < 8; ++j) p8[j] = 0;
            }
            *(u16x8*)&pt[prow * AST + chq * 8] = p8;
        }
        __syncthreads();   // B: tiles ready

        // ---- AC = (q+u) K^T
        f32x4 acS[4];
#pragma unroll
        for (int j = 0; j < 4; ++j)
#pragma unroll
            for (int r = 0; r < 4; ++r) acS[j][r] = 0.f;
#pragma unroll
        for (int j = 0; j < 4; ++j) {
            const f16x8 b0 = *(const f16x8*)&kt[(16 * j + c) * AST + 8 * g];
            const f16x8 b1 = *(const f16x8*)&kt[(16 * j + c) * AST + 32 + 8 * g];
            acS[j] = __builtin_amdgcn_mfma_f32_16x16x32_f16(aq0, b0, acS[j], 0, 0, 0);
            acS[j] = __builtin_amdgcn_mfma_f32_16x16x32_f16(aq1, b1, acS[j], 0, 0, 0);
        }

        // ---- BD: only the 5 window blocks jj = q + (3-w), q=0..4, in fp32 regs
        f32x4 bdacc[5];
#pragma unroll
        for (int q = 0; q < 5; ++q) {
#pragma unroll
            for (int r = 0; r < 4; ++r) bdacc[q][r] = 0.f;
            const int prow = 16 * (q + 3 - w) + c;          // runtime-uniform row
            const f16x8 b0 = *(const f16x8*)&pt[prow * AST + 8 * g];
            const f16x8 b1 = *(const f16x8*)&pt[prow * AST + 32 + 8 * g];
            bdacc[q] = __builtin_amdgcn_mfma_f32_16x16x32_f16(av0, b0, bdacc[q], 0, 0, 0);
            bdacc[q] = __builtin_amdgcn_mfma_f32_16x16x32_f16(av1, b1, bdacc[q], 0, 0, 0);
        }

        // ---- online softmax with in-register rel-shift
        int mk[4];
#pragma unroll
        for (int j = 0; j < 4; ++j) mk[j] = mask[b * T_SEQ + s0 + 16 * j + c];
#pragma unroll
        for (int r = 0; r < 4; ++r) {
            const int ti  = 16 * w + 4 * g + r;
            const int dlt = 15 - 4 * g - r;                 // delta
            const int csh = (c - dlt) & 15;                 // owned column class
            const int src = (lane & 48) | csh;
            const bool wrap = (c < dlt);
            float sv[4];
#pragma unroll
            for (int j = 0; j < 4; ++j) {
                const float acm = (mk[j] == 0) ? -1.0e30f : acS[j][r];
                const float acf = __shfl(acm, src, 64);
                const float bdv = wrap ? bdacc[j + 1][r] : bdacc[j][r];
                sv[j] = (acf + bdv) * 0.125f;
            }
            float mx = fmaxf(fmaxf(sv[0], sv[1]), fmaxf(sv[2], sv[3]));
            mx = fmaxf(mx, __shfl_xor(mx, 1)); mx = fmaxf(mx, __shfl_xor(mx, 2));
            mx = fmaxf(mx, __shfl_xor(mx, 4)); mx = fmaxf(mx, __shfl_xor(mx, 8));
            const float mnew = fmaxf(m_r[r], mx);
            const float corr = __expf(m_r[r] - mnew);
            m_r[r] = mnew;
            float rs = 0.f;
#pragma unroll
            for (int j = 0; j < 4; ++j) {
                const float e = (sv[j] < -1.0e28f) ? 0.f : __expf(sv[j] - mnew);
                rs += e;
                psf[ti * AST + 16 * j + csh] = (f16)e;
            }
            rs += __shfl_xor(rs, 1); rs += __shfl_xor(rs, 2);
            rs += __shfl_xor(rs, 4); rs += __shfl_xor(rs, 8);
            l_r[r] = l_r[r] * corr + rs;
#pragma unroll
            for (int n = 0; n < 4; ++n) accO[n][r] *= corr;
        }
        __syncthreads();   // D: P visible

        // ---- PV: O += P V
        const f16x8 pa0 = *(const f16x8*)&ps[(16 * w + c) * AST + 8 * g];
        const f16x8 pa1 = *(const f16x8*)&ps[(16 * w + c) * AST + 32 + 8 * g];
#pragma unroll
        for (int n = 0; n < 4; ++n) {
            const f16x8 b0 = *(const f16x8*)&vtT[(16 * n + c) * AST + 8 * g];
            const f16x8 b1 = *(const f16x8*)&vtT[(16 * n + c) * AST + 32 + 8 * g];
            accO[n] = __builtin_amdgcn_mfma_f32_16x16x32_f16(pa0, b0, accO[n], 0, 0, 0);
            accO[n] = __builtin_amdgcn_mfma_f32_16x16x32_f16(pa1, b1, accO[n], 0, 0, 0);
        }
    }

    // ---- epilogue: x split into (hi, lo) bf16 for the out-GEMM
#pragma unroll
    for (int r = 0; r < 4; ++r) {
        const float inv = (l_r[r] > 0.f) ? 1.0f / l_r[r] : 0.f;
        const int t = t0 + 16 * w + 4 * g + r;
#pragma unroll
        for (int n = 0; n < 4; ++n) {
            const float xv = accO[n][r] * inv;
            const size_t idx = ((size_t)(b * T_SEQ + t)) * FEAT + h * DKH + 16 * n + c;
            const unsigned short hp = f2bf(xv);
            xh[idx] = hp;
            xl[idx] = f2bf(xv - bf2f(hp));
        }
    }
}

// ---------------------------------------------------------------------------
extern "C" void kernel_launch(void* const* d_in, const int* in_sizes, int n_in,
                              void* d_out, int out_size, void* d_ws, size_t ws_size,
                              hipStream_t stream)
{
    (void)in_sizes; (void)n_in; (void)out_size; (void)ws_size;
    const float* query   = (const float*)d_in[0];
    const float* key_in  = (const float*)d_in[1];
    const float* value   = (const float*)d_in[2];
    const float* pos_emb = (const float*)d_in[3];
    const int*   mask    = (const int*)  d_in[4];
    const float* Wq = (const float*)d_in[5];
    const float* bq = (const float*)d_in[6];
    const float* Wk = (const float*)d_in[7];
    const float* bk = (const float*)d_in[8];
    const float* Wv = (const float*)d_in[9];
    const float* bv = (const float*)d_in[10];
    const float* Wo = (const float*)d_in[11];
    const float* bo = (const float*)d_in[12];
    const float* Wp = (const float*)d_in[13];
    const float* pbu = (const float*)d_in[14];
    const float* pbv = (const float*)d_in[15];
    float* out = (float*)d_out;

    const size_t NTOK = (size_t)8 * T_SEQ;       // 8192
    char* wsp = (char*)d_ws;
    size_t off = 0;
    auto alloc = [&](size_t bytes) { char* p = wsp + off; off += (bytes + 255) & ~255ull; return p; };

    unsigned short* qbf = (unsigned short*)alloc(NTOK * FEAT * 2);         // f16
    unsigned short* kbf = (unsigned short*)alloc(NTOK * FEAT * 2);         // f16
    unsigned short* vTb = (unsigned short*)alloc(NTOK * FEAT * 2);         // f16 [b][feat][t]
    unsigned short* pbf = (unsigned short*)alloc((size_t)2047 * FEAT * 2); // f16
    unsigned short* wh[5]; unsigned short* wl[5];
    for (int i = 0; i < 5; ++i) {
        wh[i] = (unsigned short*)alloc((size_t)FEAT * FEAT * 2);
        wl[i] = (unsigned short*)alloc((size_t)FEAT * FEAT * 2);
    }
    unsigned short* iqh = (unsigned short*)alloc(NTOK * FEAT * 2);
    unsigned short* iql = (unsigned short*)alloc(NTOK * FEAT * 2);
    unsigned short* ikh = (unsigned short*)alloc(NTOK * FEAT * 2);
    unsigned short* ikl = (unsigned short*)alloc(NTOK * FEAT * 2);
    unsigned short* ivh = (unsigned short*)alloc(NTOK * FEAT * 2);
    unsigned short* ivl = (unsigned short*)alloc(NTOK * FEAT * 2);
    unsigned short* iph = (unsigned short*)alloc((size_t)2047 * FEAT * 2);
    unsigned short* ipl = (unsigned short*)alloc((size_t)2047 * FEAT * 2);
    // x split reuses the query split (dead after the q-projection GEMM)
    unsigned short* xh = iqh;
    unsigned short* xl = iql;

    SplitPack sp;
    const float* wsrc[9] = {Wq, Wk, Wv, Wp, Wo, query, key_in, value, pos_emb};
    unsigned short* hdst[9] = {wh[0], wh[1], wh[2], wh[3], wh[4], iqh, ikh, ivh, iph};
    unsigned short* ldst[9] = {wl[0], wl[1], wl[2], wl[3], wl[4], iql, ikl, ivl, ipl};
    for (int i = 0; i < 9; ++i) {
        sp.src[i] = wsrc[i]; sp.hi[i] = hdst[i]; sp.lo[i] = ldst[i];
        sp.n4[i] = (i < 5) ? (FEAT * FEAT / 4)
                           : ((i < 8) ? (int)(NTOK * FEAT / 4) : (2047 * FEAT / 4));
    }
    split_f32<<<dim3(256, 9), 256, 0, stream>>>(sp);

    gemm_ps<1><<<dim3(64, 8), 256, 0, stream>>>(iqh, iql, wh[0], wl[0], bq, qbf, 8192, FEAT, FEAT);
    gemm_ps<1><<<dim3(64, 8), 256, 0, stream>>>(ikh, ikl, wh[1], wl[1], bk, kbf, 8192, FEAT, FEAT);
    gemm_ps<2><<<dim3(64, 8), 256, 0, stream>>>(ivh, ivl, wh[2], wl[2], bv, vTb, 8192, FEAT, FEAT);
    gemm_ps<1><<<dim3(16, 8), 256, 0, stream>>>(iph, ipl, wh[3], wl[3], nullptr, pbf, 2047, FEAT, FEAT);

    const int lds_bytes = (64 * AST * 3 + 128 * AST) * 2;   // 46080 -> 3 blocks/CU
    hipFuncSetAttribute((const void*)attn_f16,
                        hipFuncAttributeMaxDynamicSharedMemorySize, lds_bytes);
    attn_f16<<<dim3(16, 64), 256, lds_bytes, stream>>>(qbf, kbf, vTb, pbf,
                                                       mask, pbu, pbv, xh, xl);

    gemm_ps<0><<<dim3(64, 8), 256, 0, stream>>>(xh, xl, wh[4], wl[4], bo, out, 8192, FEAT, FEAT);
}